// Round 9
// baseline (219.158 us; speedup 1.0000x reference)
//
#include <hip/hip_runtime.h>

typedef __bf16 bf16_t;
typedef __attribute__((ext_vector_type(8))) __bf16 bf16x8;
typedef __attribute__((ext_vector_type(8))) unsigned short u16x8;
typedef __attribute__((ext_vector_type(4))) unsigned int u32x4;
typedef __attribute__((ext_vector_type(4))) float f32x4;

#define MFMA(a, b, c) __builtin_amdgcn_mfma_f32_16x16x32_bf16((a), (b), (c), 0, 0, 0)

__device__ __forceinline__ float bf2f(unsigned short s) {
    unsigned u = ((unsigned)s) << 16;
    return __builtin_bit_cast(float, u);
}
__device__ __forceinline__ unsigned short f2bf(float f) {
    return __builtin_bit_cast(unsigned short, (bf16_t)f);
}

// ---------------------------------------------------------------------------
// ws layout (unsigned short elements):
//   W1s: [0,16384)         W1s[cc*4096 + n*32 + kk] = W1[(cc*32+kk)*128 + n]
//   W2s: [16384,32768)     same for W2
//   W3s: [32768,34816)     W3s[o*128 + k] = W3[k*12+o] (o<12, else 0)
//   W0s: [34816,120832)    W0s[cc*4096 + n*32 + kk] = W0[f(k')][n],
//                          k'=cc*32+kk, f=(k'&7)*81+(k'>>3), 0 if k'>=648
//   inp_bf: [120832,522240) channel-last bf16: inp_bf[p*8+c] = inp[c*50176+p]
// ---------------------------------------------------------------------------
__global__ void inr_prep(const float* __restrict__ inp,
                         const float* __restrict__ W0,
                         const float* __restrict__ W1,
                         const float* __restrict__ W2,
                         const float* __restrict__ W3,
                         unsigned short* __restrict__ wsb)
{
    for (int idx = blockIdx.x * 256 + threadIdx.x; idx < 171008; idx += 334 * 256) {
        if (idx < 16384) {
            int cc = idx >> 12, rem = idx & 4095, n = rem >> 5, kk = rem & 31;
            wsb[idx] = f2bf(W1[(cc * 32 + kk) * 128 + n]);
        } else if (idx < 32768) {
            int j = idx - 16384;
            int cc = j >> 12, rem = j & 4095, n = rem >> 5, kk = rem & 31;
            wsb[idx] = f2bf(W2[(cc * 32 + kk) * 128 + n]);
        } else if (idx < 34816) {
            int r = idx - 32768;
            int o = r >> 7, k = r & 127;
            wsb[idx] = f2bf((o < 12) ? W3[k * 12 + o] : 0.f);
        } else if (idx < 120832) {
            int j = idx - 34816;
            int cc = j >> 12, rem = j & 4095, n = rem >> 5, kk = rem & 31;
            int kp = cc * 32 + kk;
            float val = 0.f;
            if (kp < 648) {
                int tt = kp >> 3, c = kp & 7;
                val = W0[(c * 81 + tt) * 128 + n];
            }
            wsb[idx] = f2bf(val);
        } else {
            int p = idx - 120832;               // point 0..50175
            const float* src = inp + p;
            bf16x8 v;
            #pragma unroll
            for (int c = 0; c < 8; ++c) v[c] = (bf16_t)src[c * 50176];
            *(bf16x8*)&wsb[120832 + p * 8] = v;
        }
    }
}

// LDS union: gather slab (layer-0 only) overlaps the two wave-private
// h-buffers (MLP phase only); the post-h0 __syncthreads separates them.
union LdsUnion {
    bf16x8 slab[1297];                 // 20752 B ([1296] = zero entry)
    unsigned short h[2][64][136];      // 34816 B: [0]=h1, [1]=h2, wave-private rows
};

// ---------------------------------------------------------------------------
// main fused kernel: 784 blocks x 256 threads; 64 points per block.
// L0: wave grid 2x2 (slab gather + prefetch, barrier-free).
// MLP: each wave owns 16 rows x full K=128 -> h1/h2 are wave-PRIVATE LDS,
//      zero barriers in the 4-iteration loop (4 barriers total per block).
// ---------------------------------------------------------------------------
__global__ __launch_bounds__(256, 2)
void inr_main(const float* __restrict__ W0g,
              const float* __restrict__ b0g,
              const float* __restrict__ b1g,
              const float* __restrict__ b2g,
              const float* __restrict__ b3g,
              const bf16_t* __restrict__ wsb,
              float* __restrict__ out)
{
    __shared__ unsigned short h0buf[64][136];  // h0_base (pre-relu, +b0), bf16
    __shared__ float ct4[4][128];              // per-iteration cell vectors
    __shared__ LdsUnion lu;

    const int tid  = threadIdx.x;
    const int lane = tid & 63;
    const int wave = tid >> 6;
    const int l15  = lane & 15;
    const int q    = lane >> 4;
    const int wm   = wave >> 1;   // L0 m-half (0/1)
    const int wn   = wave & 1;    // L0 n-half (0/1)
    const int tile = blockIdx.x;

    // block-uniform point decode: all 64 points share (u0,v0), i in {i0b,i0b+1}
    const int Bi = tile >> 4;
    const int u0 = Bi / 7, v0 = Bi - 7 * u0;
    const int i0b = (tile & 15) * 2;

    const bf16x8* W0s8 = (const bf16x8*)&wsb[34816];
    const bf16x8* W1s8 = (const bf16x8*)&wsb[0];
    const bf16x8* W2s8 = (const bf16x8*)&wsb[16384];
    const bf16x8* W3s8 = (const bf16x8*)&wsb[32768];
    const bf16x8* inpb8 = (const bf16x8*)&wsb[120832];  // [plane_point][8ch]

    // ---- one-time staging: ct4 (read only after the post-h0 barrier) ----
    if (tid < 128) {
        int k = tid;
        float wa = W0g[716 * 128 + k] + W0g[717 * 128 + k];
        float wb = W0g[718 * 128 + k] + W0g[719 * 128 + k];
        float p = 32.f;
        #pragma unroll
        for (int it = 0; it < 4; ++it) { ct4[it][k] = p * wa + wb; p *= 32.f; }
    }

    // ---- slab fill: 9 views x 4 rows x 36 cols, zero-padded OOB ----
    for (int s = tid; s < 1297; s += 256) {
        bf16x8 v;
        #pragma unroll
        for (int e = 0; e < 8; ++e) v[e] = (bf16_t)0.f;
        if (s < 1296) {
            int vd = s / 144, rem = s - vd * 144;
            int ri = rem / 36, jc = rem - ri * 36;
            int uu = u0 + vd / 3 - 1, vv = v0 + (vd - (vd / 3) * 3) - 1;
            int ii = i0b - 1 + ri, jj = jc - 1;
            if ((unsigned)uu < 7u && (unsigned)vv < 7u &&
                (unsigned)ii < 32u && (unsigned)jj < 32u)
                v = inpb8[((uu * 7 + vv) << 10) + (ii << 5) + jj];
        }
        lu.slab[s] = v;
    }

    // ---- per-lane constants ----
    float b0v[4];
    #pragma unroll
    for (int nb = 0; nb < 4; ++nb) b0v[nb] = b0g[wn * 64 + nb * 16 + l15];
    float b1v[8], b2v[8];
    #pragma unroll
    for (int nb = 0; nb < 8; ++nb) {
        b1v[nb] = b1g[nb * 16 + l15];
        b2v[nb] = b2g[nb * 16 + l15];
    }
    // MLP: this wave owns rows wave*16 .. wave*16+15; lane's A-row:
    const int myrow = wave * 16 + l15;
    const int pprow = (tile & 15) * 64 + myrow;
    const float gl = (pprow < 2) ? 0.0625f : ((pprow < 4) ? (2.f / 7.f) : 1.f);
    const bool fastg = (tile & 15) != 0;   // all rows have g == 1

    int nidx4[4];
    #pragma unroll
    for (int nb = 0; nb < 4; ++nb) nidx4[nb] = (wn * 64 + nb * 16 + l15) * 4 + q;

    __syncthreads();   // slab ready

    // A-frag slab index for chunk cc, m-block mb (t>=81 -> zero slot 1296)
    auto slab_idx = [&](int cc, int mb) -> int {
        int t = cc * 4 + q;
        if (t >= 81) return 1296;
        int s = t / 9, a = t - 9 * s;
        int ki = s / 3, kj = s - 3 * ki;
        return a * 144 + (wm + ki) * 36 + (mb * 16 + l15 + kj);
    };

    // ================= layer 0: depth-1 pipelined, barrier-free =============
    f32x4 acc0[2][4];
    #pragma unroll
    for (int mb = 0; mb < 2; ++mb)
        #pragma unroll
        for (int nb = 0; nb < 4; ++nb)
            acc0[mb][nb] = (f32x4){0.f, 0.f, 0.f, 0.f};

    bf16x8 wfc[4], wfn[4], afc[2], afn[2];
    #pragma unroll
    for (int nb = 0; nb < 4; ++nb) wfc[nb] = W0s8[nidx4[nb]];
    afc[0] = lu.slab[slab_idx(0, 0)];
    afc[1] = lu.slab[slab_idx(0, 1)];

    for (int cc = 0; cc < 21; ++cc) {
        int nc = cc + 1;
        if (nc < 21) {
            #pragma unroll
            for (int nb = 0; nb < 4; ++nb) wfn[nb] = W0s8[nc * 512 + nidx4[nb]];
            afn[0] = lu.slab[slab_idx(nc, 0)];
            afn[1] = lu.slab[slab_idx(nc, 1)];
        }
        #pragma unroll
        for (int mb = 0; mb < 2; ++mb)
            #pragma unroll
            for (int nb = 0; nb < 4; ++nb)
                acc0[mb][nb] = MFMA(afc[mb], wfc[nb], acc0[mb][nb]);
        #pragma unroll
        for (int nb = 0; nb < 4; ++nb) wfc[nb] = wfn[nb];
        afc[0] = afn[0]; afc[1] = afn[1];
    }

    // h0_base = acc0 + b0 -> bf16 LDS
    #pragma unroll
    for (int mb = 0; mb < 2; ++mb)
        #pragma unroll
        for (int nb = 0; nb < 4; ++nb) {
            int col = wn * 64 + nb * 16 + l15;
            #pragma unroll
            for (int r = 0; r < 4; ++r)
                h0buf[wm * 32 + mb * 16 + q * 4 + r][col] = f2bf(acc0[mb][nb][r] + b0v[nb]);
        }

    // hoist W3 fragments (reused every iteration)
    bf16x8 wf3[4];
    #pragma unroll
    for (int cc = 0; cc < 4; ++cc) wf3[cc] = W3s8[l15 * 16 + cc * 4 + q];

    __syncthreads();   // h0 complete; slab space becomes wave-private h1/h2

    // ================= 4 iterations, ZERO barriers ==========================
    f32x4 outacc = (f32x4){0.f, 0.f, 0.f, 0.f};

    for (int it = 0; it < 4; ++it) {
        // ---- layer 1: A = relu(h0[myrow] + g*ct_it); full N=128 per wave ----
        f32x4 acc1[8];
        #pragma unroll
        for (int nb = 0; nb < 8; ++nb) acc1[nb] = (f32x4){0.f, 0.f, 0.f, 0.f};

        #pragma unroll
        for (int cc = 0; cc < 4; ++cc) {
            int k0 = cc * 32 + q * 8;
            f32x4 ct0 = *(const f32x4*)&ct4[it][k0];
            f32x4 ct1 = *(const f32x4*)&ct4[it][k0 + 4];
            u16x8 hv = *(const u16x8*)&h0buf[myrow][k0];
            bf16x8 af;
            if (fastg) {
                #pragma unroll
                for (int e = 0; e < 8; ++e) {
                    float ctv = (e < 4) ? ct0[e] : ct1[e - 4];
                    af[e] = (bf16_t)fmaxf(bf2f(hv[e]) + ctv, 0.f);
                }
            } else {
                #pragma unroll
                for (int e = 0; e < 8; ++e) {
                    float ctv = (e < 4) ? ct0[e] : ct1[e - 4];
                    af[e] = (bf16_t)fmaxf(fmaf(gl, ctv, bf2f(hv[e])), 0.f);
                }
            }
            #pragma unroll
            for (int nb = 0; nb < 8; ++nb) {
                bf16x8 wf = W1s8[cc * 512 + (nb * 16 + l15) * 4 + q];
                acc1[nb] = MFMA(af, wf, acc1[nb]);
            }
        }
        // h1 = relu(acc1 + b1) -> wave-private rows of lu.h[0]
        #pragma unroll
        for (int nb = 0; nb < 8; ++nb) {
            int col = nb * 16 + l15;
            #pragma unroll
            for (int r = 0; r < 4; ++r)
                lu.h[0][wave * 16 + q * 4 + r][col] =
                    f2bf(fmaxf(acc1[nb][r] + b1v[nb], 0.f));
        }

        // ---- layer 2 (reads wave-private h1; lgkmcnt order, no barrier) ----
        f32x4 acc2[8];
        #pragma unroll
        for (int nb = 0; nb < 8; ++nb) acc2[nb] = (f32x4){0.f, 0.f, 0.f, 0.f};

        #pragma unroll
        for (int cc = 0; cc < 4; ++cc) {
            int k0 = cc * 32 + q * 8;
            bf16x8 af = *(const bf16x8*)&lu.h[0][myrow][k0];
            #pragma unroll
            for (int nb = 0; nb < 8; ++nb) {
                bf16x8 wf = W2s8[cc * 512 + (nb * 16 + l15) * 4 + q];
                acc2[nb] = MFMA(af, wf, acc2[nb]);
            }
        }
        // h2 = relu(acc2 + b2) -> wave-private rows of lu.h[1]
        #pragma unroll
        for (int nb = 0; nb < 8; ++nb) {
            int col = nb * 16 + l15;
            #pragma unroll
            for (int r = 0; r < 4; ++r)
                lu.h[1][wave * 16 + q * 4 + r][col] =
                    f2bf(fmaxf(acc2[nb][r] + b2v[nb], 0.f));
        }

        // ---- layer 3: reads wave-private h2 ----
        #pragma unroll
        for (int cc = 0; cc < 4; ++cc) {
            int k0 = cc * 32 + q * 8;
            bf16x8 af = *(const bf16x8*)&lu.h[1][myrow][k0];
            outacc = MFMA(af, wf3[cc], outacc);  // accumulates across cc AND it
        }
    }

    __syncthreads();   // all waves done with h0 before sf reuse

    // ======== epilogue: LDS transpose -> fully-coalesced float4 stores ======
    {
        float* sf = (float*)h0buf;           // 64 x 13 floats
        if (l15 < 12) {
            float b3v = b3g[l15];
            #pragma unroll
            for (int r = 0; r < 4; ++r)
                sf[(wave * 16 + q * 4 + r) * 13 + l15] = 0.25f * outacc[r] + b3v;
        }
        __syncthreads();
        if (tid < 192) {
            int ch = tid >> 6, rr = (tid >> 4) & 3, cg = tid & 15;
            int il = rr >> 1, s = rr & 1;
            f32x4 v;
            #pragma unroll
            for (int e = 0; e < 4; ++e) {
                int col = cg * 4 + e;
                int j = col >> 1, t2 = col & 1;
                v[e] = sf[(il * 32 + j) * 13 + ch * 4 + s * 2 + t2];
            }
            int row = 2 * (i0b + il) + s;
            *(f32x4*)&out[((ch * 7 + u0) * 7 + v0) * 4096 + row * 64 + cg * 4] = v;
        }
    }
}

extern "C" void kernel_launch(void* const* d_in, const int* in_sizes, int n_in,
                              void* d_out, int out_size, void* d_ws, size_t ws_size,
                              hipStream_t stream)
{
    (void)in_sizes; (void)n_in; (void)out_size; (void)ws_size;
    const float* inp = (const float*)d_in[0];
    const float* W0  = (const float*)d_in[1];
    const float* b0  = (const float*)d_in[2];
    const float* W1  = (const float*)d_in[3];
    const float* b1  = (const float*)d_in[4];
    const float* W2  = (const float*)d_in[5];
    const float* b2  = (const float*)d_in[6];
    const float* W3  = (const float*)d_in[7];
    const float* b3  = (const float*)d_in[8];
    float* out = (float*)d_out;
    unsigned short* wsb = (unsigned short*)d_ws;

    inr_prep<<<334, 256, 0, stream>>>(inp, W0, W1, W2, W3, wsb);
    inr_main<<<784, 256, 0, stream>>>(W0, b0, b1, b2, b3, (const bf16_t*)wsb, out);
}

// Round 10
// 120.882 us; speedup vs baseline: 1.8130x; 1.8130x over previous
//
#include <hip/hip_runtime.h>

typedef __bf16 bf16_t;
typedef __attribute__((ext_vector_type(8))) __bf16 bf16x8;
typedef __attribute__((ext_vector_type(8))) unsigned short u16x8;
typedef __attribute__((ext_vector_type(4))) unsigned int u32x4;
typedef __attribute__((ext_vector_type(4))) float f32x4;

#define MFMA(a, b, c) __builtin_amdgcn_mfma_f32_16x16x32_bf16((a), (b), (c), 0, 0, 0)

__device__ __forceinline__ float bf2f(unsigned short s) {
    unsigned u = ((unsigned)s) << 16;
    return __builtin_bit_cast(float, u);
}
__device__ __forceinline__ unsigned short f2bf(float f) {
    return __builtin_bit_cast(unsigned short, (bf16_t)f);
}
// packed 2x f32 -> bf16
__device__ __forceinline__ unsigned pkbf(float x, float y) {
    return (unsigned)f2bf(x) | ((unsigned)f2bf(y) << 16);
}

// ---------------------------------------------------------------------------
// ws layout (unsigned short elements):
//   W1s: [0,16384)         W1s[cc*4096 + n*32 + kk] = W1[(cc*32+kk)*128 + n]
//   W2s: [16384,32768)     same for W2
//   W3s: [32768,34816)     W3s[o*128 + k] = W3[k*12+o] (o<12, else 0)
//   W0s: [34816,120832)    W0s[cc*4096 + n*32 + kk] = W0[f(k')][n],
//                          k'=cc*32+kk, f=(k'&7)*81+(k'>>3), 0 if k'>=648
//   inp_bf: [120832,522240) channel-last bf16: inp_bf[p*8+c] = inp[c*50176+p]
// ---------------------------------------------------------------------------
__global__ void inr_prep(const float* __restrict__ inp,
                         const float* __restrict__ W0,
                         const float* __restrict__ W1,
                         const float* __restrict__ W2,
                         const float* __restrict__ W3,
                         unsigned short* __restrict__ wsb)
{
    for (int idx = blockIdx.x * 256 + threadIdx.x; idx < 171008; idx += 334 * 256) {
        if (idx < 16384) {
            int cc = idx >> 12, rem = idx & 4095, n = rem >> 5, kk = rem & 31;
            wsb[idx] = f2bf(W1[(cc * 32 + kk) * 128 + n]);
        } else if (idx < 32768) {
            int j = idx - 16384;
            int cc = j >> 12, rem = j & 4095, n = rem >> 5, kk = rem & 31;
            wsb[idx] = f2bf(W2[(cc * 32 + kk) * 128 + n]);
        } else if (idx < 34816) {
            int r = idx - 32768;
            int o = r >> 7, k = r & 127;
            wsb[idx] = f2bf((o < 12) ? W3[k * 12 + o] : 0.f);
        } else if (idx < 120832) {
            int j = idx - 34816;
            int cc = j >> 12, rem = j & 4095, n = rem >> 5, kk = rem & 31;
            int kp = cc * 32 + kk;
            float val = 0.f;
            if (kp < 648) {
                int tt = kp >> 3, c = kp & 7;
                val = W0[(c * 81 + tt) * 128 + n];
            }
            wsb[idx] = f2bf(val);
        } else {
            int p = idx - 120832;               // point 0..50175
            const float* src = inp + p;
            bf16x8 v;
            #pragma unroll
            for (int c = 0; c < 8; ++c) v[c] = (bf16_t)src[c * 50176];
            *(bf16x8*)&wsb[120832 + p * 8] = v;
        }
    }
}

// LDS union: gather slab (layer-0 only) overlaps the h2 buffer (MLP phase
// only); the post-h0 __syncthreads separates all slab reads from h2 writes.
union Lds2 {
    bf16x8 slab[1297];                 // 20752 B ([1296] = zero entry)
    unsigned short h2[64][136];        // 17408 B
};

// ---------------------------------------------------------------------------
// main fused kernel: 784 blocks x 256 threads; 64 points per block.
// Wave grid 2x2 (R5 structure). h2 in its own (union) buffer -> the
// write-after-read barriers disappear: 2 barriers per MLP iteration.
// ---------------------------------------------------------------------------
__global__ __launch_bounds__(256, 2)
void inr_main(const float* __restrict__ W0g,
              const float* __restrict__ b0g,
              const float* __restrict__ b1g,
              const float* __restrict__ b2g,
              const float* __restrict__ b3g,
              const bf16_t* __restrict__ wsb,
              float* __restrict__ out)
{
    __shared__ unsigned short h0buf[64][136];  // h0_base (pre-relu, +b0), bf16
    __shared__ unsigned short h1buf[64][136];  // h1, bf16
    __shared__ float ct4[4][128];              // per-iteration cell vectors
    __shared__ Lds2 lu;                        // slab / h2

    const int tid  = threadIdx.x;
    const int lane = tid & 63;
    const int wave = tid >> 6;
    const int l15  = lane & 15;
    const int q    = lane >> 4;
    const int wm   = wave >> 1;   // m-half (0/1)
    const int wn   = wave & 1;    // n-half (0/1)
    const int tile = blockIdx.x;

    // block-uniform point decode: all 64 points share (u0,v0), i in {i0b,i0b+1}
    const int Bi = tile >> 4;
    const int u0 = Bi / 7, v0 = Bi - 7 * u0;
    const int i0b = (tile & 15) * 2;

    const bf16x8* W0s8 = (const bf16x8*)&wsb[34816];
    const bf16x8* W1s8 = (const bf16x8*)&wsb[0];
    const bf16x8* W2s8 = (const bf16x8*)&wsb[16384];
    const bf16x8* W3s8 = (const bf16x8*)&wsb[32768];
    const bf16x8* inpb8 = (const bf16x8*)&wsb[120832];  // [plane_point][8ch]

    // ---- one-time staging: ct4 (read only after the post-h0 barrier) ----
    if (tid < 128) {
        int k = tid;
        float wa = W0g[716 * 128 + k] + W0g[717 * 128 + k];
        float wb = W0g[718 * 128 + k] + W0g[719 * 128 + k];
        float p = 32.f;
        #pragma unroll
        for (int it = 0; it < 4; ++it) { ct4[it][k] = p * wa + wb; p *= 32.f; }
    }

    // ---- slab fill: 9 views x 4 rows x 36 cols, zero-padded OOB ----
    for (int s = tid; s < 1297; s += 256) {
        bf16x8 v;
        #pragma unroll
        for (int e = 0; e < 8; ++e) v[e] = (bf16_t)0.f;
        if (s < 1296) {
            int vd = s / 144, rem = s - vd * 144;
            int ri = rem / 36, jc = rem - ri * 36;
            int uu = u0 + vd / 3 - 1, vv = v0 + (vd - (vd / 3) * 3) - 1;
            int ii = i0b - 1 + ri, jj = jc - 1;
            if ((unsigned)uu < 7u && (unsigned)vv < 7u &&
                (unsigned)ii < 32u && (unsigned)jj < 32u)
                v = inpb8[((uu * 7 + vv) << 10) + (ii << 5) + jj];
        }
        lu.slab[s] = v;
    }

    // ---- per-lane constants ----
    float b0v[4], b1v[4], b2v[4];
    #pragma unroll
    for (int nb = 0; nb < 4; ++nb) {
        int col = wn * 64 + nb * 16 + l15;
        b0v[nb] = b0g[col]; b1v[nb] = b1g[col]; b2v[nb] = b2g[col];
    }
    float gln[2];
    #pragma unroll
    for (int mb = 0; mb < 2; ++mb) {
        int ppt = (tile & 15) * 64 + wm * 32 + mb * 16 + l15;
        gln[mb] = (ppt < 2) ? 0.0625f : ((ppt < 4) ? (2.f / 7.f) : 1.f);
    }
    const bool fastg = (tile & 15) != 0;   // all 64 rows have g == 1

    int nidx4[4];
    #pragma unroll
    for (int nb = 0; nb < 4; ++nb) nidx4[nb] = (wn * 64 + nb * 16 + l15) * 4 + q;

    __syncthreads();   // slab ready

    // A-frag slab index for chunk cc, m-block mb (t>=81 -> zero slot 1296)
    auto slab_idx = [&](int cc, int mb) -> int {
        int t = cc * 4 + q;
        if (t >= 81) return 1296;
        int s = t / 9, a = t - 9 * s;
        int ki = s / 3, kj = s - 3 * ki;
        return a * 144 + (wm + ki) * 36 + (mb * 16 + l15 + kj);
    };

    // ================= layer 0: depth-1 pipelined, barrier-free =============
    f32x4 acc0[2][4];
    #pragma unroll
    for (int mb = 0; mb < 2; ++mb)
        #pragma unroll
        for (int nb = 0; nb < 4; ++nb)
            acc0[mb][nb] = (f32x4){0.f, 0.f, 0.f, 0.f};

    bf16x8 wfc[4], wfn[4], afc[2], afn[2];
    #pragma unroll
    for (int nb = 0; nb < 4; ++nb) wfc[nb] = W0s8[nidx4[nb]];
    afc[0] = lu.slab[slab_idx(0, 0)];
    afc[1] = lu.slab[slab_idx(0, 1)];

    for (int cc = 0; cc < 21; ++cc) {
        int nc = cc + 1;
        if (nc < 21) {
            #pragma unroll
            for (int nb = 0; nb < 4; ++nb) wfn[nb] = W0s8[nc * 512 + nidx4[nb]];
            afn[0] = lu.slab[slab_idx(nc, 0)];
            afn[1] = lu.slab[slab_idx(nc, 1)];
        }
        #pragma unroll
        for (int mb = 0; mb < 2; ++mb)
            #pragma unroll
            for (int nb = 0; nb < 4; ++nb)
                acc0[mb][nb] = MFMA(afc[mb], wfc[nb], acc0[mb][nb]);
        #pragma unroll
        for (int nb = 0; nb < 4; ++nb) wfc[nb] = wfn[nb];
        afc[0] = afn[0]; afc[1] = afn[1];
    }

    // h0_base = acc0 + b0 -> bf16 LDS
    #pragma unroll
    for (int mb = 0; mb < 2; ++mb)
        #pragma unroll
        for (int nb = 0; nb < 4; ++nb) {
            int col = wn * 64 + nb * 16 + l15;
            #pragma unroll
            for (int r = 0; r < 4; ++r)
                h0buf[wm * 32 + mb * 16 + q * 4 + r][col] = f2bf(acc0[mb][nb][r] + b0v[nb]);
        }

    // hoist W3 fragments (reused every iteration)
    bf16x8 wf3[4];
    #pragma unroll
    for (int cc = 0; cc < 4; ++cc) wf3[cc] = W3s8[l15 * 16 + cc * 4 + q];

    __syncthreads();   // h0 complete; slab space becomes h2 space

    // ================= 4 iterations, 2 barriers each ========================
    f32x4 outacc = (f32x4){0.f, 0.f, 0.f, 0.f};

    for (int it = 0; it < 4; ++it) {
        // ---- layer 1: A = relu(h0 + g*ct_it) built on the fly (pk-cvt) ----
        f32x4 acc1[2][4];
        #pragma unroll
        for (int mb = 0; mb < 2; ++mb)
            #pragma unroll
            for (int nb = 0; nb < 4; ++nb) acc1[mb][nb] = (f32x4){0.f, 0.f, 0.f, 0.f};

        #pragma unroll
        for (int cc = 0; cc < 4; ++cc) {
            int k0 = cc * 32 + q * 8;
            f32x4 ct0 = *(const f32x4*)&ct4[it][k0];
            f32x4 ct1 = *(const f32x4*)&ct4[it][k0 + 4];
            bf16x8 wf[4];
            #pragma unroll
            for (int nb = 0; nb < 4; ++nb)
                wf[nb] = W1s8[cc * 512 + nidx4[nb]];
            #pragma unroll
            for (int mb = 0; mb < 2; ++mb) {
                u16x8 hv = *(const u16x8*)&h0buf[wm * 32 + mb * 16 + l15][k0];
                u32x4 av;
                if (fastg) {
                    av[0] = pkbf(fmaxf(bf2f(hv[0]) + ct0[0], 0.f),
                                 fmaxf(bf2f(hv[1]) + ct0[1], 0.f));
                    av[1] = pkbf(fmaxf(bf2f(hv[2]) + ct0[2], 0.f),
                                 fmaxf(bf2f(hv[3]) + ct0[3], 0.f));
                    av[2] = pkbf(fmaxf(bf2f(hv[4]) + ct1[0], 0.f),
                                 fmaxf(bf2f(hv[5]) + ct1[1], 0.f));
                    av[3] = pkbf(fmaxf(bf2f(hv[6]) + ct1[2], 0.f),
                                 fmaxf(bf2f(hv[7]) + ct1[3], 0.f));
                } else {
                    float g = gln[mb];
                    av[0] = pkbf(fmaxf(fmaf(g, ct0[0], bf2f(hv[0])), 0.f),
                                 fmaxf(fmaf(g, ct0[1], bf2f(hv[1])), 0.f));
                    av[1] = pkbf(fmaxf(fmaf(g, ct0[2], bf2f(hv[2])), 0.f),
                                 fmaxf(fmaf(g, ct0[3], bf2f(hv[3])), 0.f));
                    av[2] = pkbf(fmaxf(fmaf(g, ct1[0], bf2f(hv[4])), 0.f),
                                 fmaxf(fmaf(g, ct1[1], bf2f(hv[5])), 0.f));
                    av[3] = pkbf(fmaxf(fmaf(g, ct1[2], bf2f(hv[6])), 0.f),
                                 fmaxf(fmaf(g, ct1[3], bf2f(hv[7])), 0.f));
                }
                bf16x8 af = __builtin_bit_cast(bf16x8, av);
                #pragma unroll
                for (int nb = 0; nb < 4; ++nb)
                    acc1[mb][nb] = MFMA(af, wf[nb], acc1[mb][nb]);
            }
        }
        // h1 = relu(acc1 + b1) -> h1buf
        #pragma unroll
        for (int mb = 0; mb < 2; ++mb)
            #pragma unroll
            for (int nb = 0; nb < 4; ++nb) {
                int col = wn * 64 + nb * 16 + l15;
                #pragma unroll
                for (int r = 0; r < 4; ++r)
                    h1buf[wm * 32 + mb * 16 + q * 4 + r][col] =
                        f2bf(fmaxf(acc1[mb][nb][r] + b1v[nb], 0.f));
            }
        __syncthreads();   // (1) h1 ready

        // ---- layer 2: reads h1, writes h2 (separate buffer) ----
        f32x4 acc2[2][4];
        #pragma unroll
        for (int mb = 0; mb < 2; ++mb)
            #pragma unroll
            for (int nb = 0; nb < 4; ++nb) acc2[mb][nb] = (f32x4){0.f, 0.f, 0.f, 0.f};

        #pragma unroll
        for (int cc = 0; cc < 4; ++cc) {
            int k0 = cc * 32 + q * 8;
            bf16x8 wf[4];
            #pragma unroll
            for (int nb = 0; nb < 4; ++nb)
                wf[nb] = W2s8[cc * 512 + nidx4[nb]];
            #pragma unroll
            for (int mb = 0; mb < 2; ++mb) {
                bf16x8 af = *(const bf16x8*)&h1buf[wm * 32 + mb * 16 + l15][k0];
                #pragma unroll
                for (int nb = 0; nb < 4; ++nb)
                    acc2[mb][nb] = MFMA(af, wf[nb], acc2[mb][nb]);
            }
        }
        // h2 = relu(acc2 + b2) -> lu.h2
        #pragma unroll
        for (int mb = 0; mb < 2; ++mb)
            #pragma unroll
            for (int nb = 0; nb < 4; ++nb) {
                int col = wn * 64 + nb * 16 + l15;
                #pragma unroll
                for (int r = 0; r < 4; ++r)
                    lu.h2[wm * 32 + mb * 16 + q * 4 + r][col] =
                        f2bf(fmaxf(acc2[mb][nb][r] + b2v[nb], 0.f));
            }
        __syncthreads();   // (2) h2 ready; also fences h1 reads vs next L1 write

        // ---- layer 3: wave m-split (16 rows each), register W3 frags ----
        #pragma unroll
        for (int cc = 0; cc < 4; ++cc) {
            int k0 = cc * 32 + q * 8;
            bf16x8 af = *(const bf16x8*)&lu.h2[wave * 16 + l15][k0];
            outacc = MFMA(af, wf3[cc], outacc);  // accumulates across cc AND it
        }
        // no barrier: next L1 writes h1 (not h2); next h2 write is after (1)
    }

    __syncthreads();   // all h0 reads done before sf reuse

    // ======== epilogue: LDS transpose -> fully-coalesced float4 stores ======
    {
        float* sf = (float*)h0buf;           // 64 x 13 floats
        if (l15 < 12) {
            float b3v = b3g[l15];
            #pragma unroll
            for (int r = 0; r < 4; ++r)
                sf[(wave * 16 + q * 4 + r) * 13 + l15] = 0.25f * outacc[r] + b3v;
        }
        __syncthreads();
        if (tid < 192) {
            int ch = tid >> 6, rr = (tid >> 4) & 3, cg = tid & 15;
            int il = rr >> 1, s = rr & 1;
            f32x4 v;
            #pragma unroll
            for (int e = 0; e < 4; ++e) {
                int col = cg * 4 + e;
                int j = col >> 1, t2 = col & 1;
                v[e] = sf[(il * 32 + j) * 13 + ch * 4 + s * 2 + t2];
            }
            int row = 2 * (i0b + il) + s;
            *(f32x4*)&out[((ch * 7 + u0) * 7 + v0) * 4096 + row * 64 + cg * 4] = v;
        }
    }
}

extern "C" void kernel_launch(void* const* d_in, const int* in_sizes, int n_in,
                              void* d_out, int out_size, void* d_ws, size_t ws_size,
                              hipStream_t stream)
{
    (void)in_sizes; (void)n_in; (void)out_size; (void)ws_size;
    const float* inp = (const float*)d_in[0];
    const float* W0  = (const float*)d_in[1];
    const float* b0  = (const float*)d_in[2];
    const float* W1  = (const float*)d_in[3];
    const float* b1  = (const float*)d_in[4];
    const float* W2  = (const float*)d_in[5];
    const float* b2  = (const float*)d_in[6];
    const float* W3  = (const float*)d_in[7];
    const float* b3  = (const float*)d_in[8];
    float* out = (float*)d_out;
    unsigned short* wsb = (unsigned short*)d_ws;

    inr_prep<<<334, 256, 0, stream>>>(inp, W0, W1, W2, W3, wsb);
    inr_main<<<784, 256, 0, stream>>>(W0, b0, b1, b2, b3, (const bf16_t*)wsb, out);
}